// Round 6
// baseline (264.017 us; speedup 1.0000x reference)
//
#include <hip/hip_runtime.h>
#include <hip/hip_bf16.h>
#include <math.h>

#define N_NODES 50000
#define N_EDGES 800000
#define IN_DIM 256
#define HID 32
#define HEADS 4
#define OUT_DIM 64

#define SCAN_CHUNK 1024
#define SCAN_BLOCKS ((N_NODES + SCAN_CHUNK - 1) / SCAN_CHUNK)  // 49
#define HIST_BLOCKS ((N_EDGES + 255) / 256)   // 3125
#define MBLK ((N_NODES + 63) / 64)            // 782

typedef __attribute__((ext_vector_type(8))) short bf16x8;
typedef __attribute__((ext_vector_type(4))) float f32x4;

__device__ __forceinline__ float lrelu(float e) { return e > 0.f ? e : 0.01f * e; }
__device__ __forceinline__ float bflo(unsigned u) { return __uint_as_float(u << 16); }
__device__ __forceinline__ float bfhi(unsigned u) { return __uint_as_float(u & 0xffff0000u); }

// RNE float->bf16
__device__ __forceinline__ unsigned short rne_bf16(float x) {
    unsigned u = __float_as_uint(x);
    unsigned r = u + 0x7fffu + ((u >> 16) & 1u);
    return (unsigned short)(r >> 16);
}

// A-operand split (truncate hi + residual)
__device__ __forceinline__ void splitf(float x, short& hi, short& lo) {
    unsigned u = __float_as_uint(x);
    unsigned short h = (unsigned short)(u >> 16);
    float hf = __uint_as_float(((unsigned)h) << 16);
    float l = x - hf;
    unsigned short lb = (unsigned short)(__float_as_uint(l) >> 16);
    hi = (short)h;
    lo = (short)lb;
}

// ---------------- B-pack prep body ----------------
// NOTE z1b/h1b use an internal within-head channel permutation:
//   stored position p(ch) = (ch>>5)*32 + (ch&15)*2 + ((ch>>4)&1)
// (chosen so proj1's epilogue stores are contiguous dwords). agg1 is
// position-blind (head of every 16B block is preserved: (c16*4)>>4 == c16>>2).
// Only consequence: B2 pack slot k must fetch W2's TRUE row
//   ck(k) = (2*(k>>5)+(k&1))*16 + ((k&31)>>1).

__device__ __forceinline__ void prep_body(int k, int c,
        const float* __restrict__ W1, const float* __restrict__ a1,
        const float* __restrict__ W2, const float* __restrict__ a2,
        unsigned short* __restrict__ B1h, unsigned short* __restrict__ B1l,
        unsigned short* __restrict__ B2h, unsigned short* __restrict__ B2l) {
    if (c < 144) {
        float val = 0.f;
        if (c < 128) {
            val = W1[(size_t)(c >> 5) * IN_DIM * HID + (size_t)k * HID + (c & 31)];
        } else if (c < 136) {
            int j = c - 128;
            int hd = (j < 4) ? j : (j - 4);
            int off = (j < 4) ? 0 : HID;
            const float* Wp = W1 + (size_t)hd * IN_DIM * HID + (size_t)k * HID;
            const float* ap = a1 + hd * 2 * HID + off;
            float s = 0.f;
            for (int o = 0; o < HID; o++) s += Wp[o] * ap[o];
            val = s;
        }
        unsigned short hi = rne_bf16(val);
        float hf = __uint_as_float(((unsigned)hi) << 16);
        unsigned short lo = rne_bf16(val - hf);
        int s_ = k >> 5, q = (k >> 3) & 3, j8 = k & 7;
        int nt = c >> 4, L = q * 16 + (c & 15);
        size_t idx = (((size_t)s_ * 9 + nt) * 64 + L) * 8 + j8;
        B1h[idx] = hi;
        B1l[idx] = lo;
    } else if (c >= 160 && c < 240 && k < 128) {
        int c2 = c - 160;
        // permuted h1 channel for this K-slot (see header comment)
        int ck = (2 * (k >> 5) + (k & 1)) * 16 + ((k & 31) >> 1);
        float val = 0.f;
        if (c2 < 64) {
            val = W2[(size_t)ck * OUT_DIM + c2];
        } else if (c2 < 66) {
            const float* ap = a2 + (c2 - 64) * OUT_DIM;
            const float* Wp = W2 + (size_t)ck * OUT_DIM;
            float s = 0.f;
            for (int o = 0; o < OUT_DIM; o++) s += Wp[o] * ap[o];
            val = s;
        }
        unsigned short hi = rne_bf16(val);
        float hf = __uint_as_float(((unsigned)hi) << 16);
        unsigned short lo = rne_bf16(val - hf);
        int s_ = k >> 5, q = (k >> 3) & 3, j8 = k & 7;
        int nt = c2 >> 4, L = q * 16 + (c2 & 15);
        size_t idx = (((size_t)s_ * 5 + nt) * 64 + L) * 8 + j8;
        B2h[idx] = hi;
        B2l[idx] = lo;
    }
}

// ---------------- K1: prep (blocks 0..255) + histogram (blocks 256..) ----------------
// count pre-zeroed by hipMemsetAsync; prep and hist touch disjoint data.
// No rank array: the per-dst slot is re-derived in scatter via cursor atomics.

__global__ void __launch_bounds__(256) prep_hist_kernel(
        const float* __restrict__ W1, const float* __restrict__ a1,
        const float* __restrict__ W2, const float* __restrict__ a2,
        unsigned short* __restrict__ B1h, unsigned short* __restrict__ B1l,
        unsigned short* __restrict__ B2h, unsigned short* __restrict__ B2l,
        const int* __restrict__ dst, int* __restrict__ count) {
    int bid = blockIdx.x;
    if (bid < 256) {
        prep_body(bid, threadIdx.x, W1, a1, W2, a2, B1h, B1l, B2h, B2l);
    } else {
        int i = (bid - 256) * 256 + threadIdx.x;
        if (i < N_EDGES) atomicAdd(&count[dst[i]], 1);
    }
}

// ---------------- scan1: per-chunk exclusive scan + cross-chunk atomic prefix ----------
// Global offset of node v = rs_local[v] + bs_prefix[v>>10].
// cursor gets a second copy of rs_local for scatter's atomic slot assignment.

__device__ __forceinline__ void scan1_body(int bid, int t, const int* __restrict__ count,
        int* __restrict__ rs_local, int* __restrict__ cursor,
        int* __restrict__ bs_prefix, int* sdata) {
    int base = bid * SCAN_CHUNK + t * 4;
    int v[4];
    int s = 0;
#pragma unroll
    for (int j = 0; j < 4; j++) {
        int idx = base + j;
        int x = (idx < N_NODES) ? count[idx] : 0;
        v[j] = x;
        s += x;
    }
    sdata[t] = s;
    __syncthreads();
    for (int off = 1; off < 256; off <<= 1) {
        int u = (t >= off) ? sdata[t - off] : 0;
        __syncthreads();
        sdata[t] += u;
        __syncthreads();
    }
    int excl = sdata[t] - s;
#pragma unroll
    for (int j = 0; j < 4; j++) {
        int idx = base + j;
        if (idx < N_NODES) {
            rs_local[idx] = excl;
            cursor[idx] = excl;
        }
        excl += v[j];
    }
    // cross-chunk prefix: add my total into all later chunks
    if (t > bid && t < SCAN_BLOCKS) atomicAdd(&bs_prefix[t], sdata[255]);
}

// ---------------- Layer-1 projection body: one wave handles rows n0..n0+15 ----------------

__device__ __forceinline__ void proj1_body(int n0, int L,
        const float* __restrict__ h, const unsigned short* __restrict__ Bh,
        const unsigned short* __restrict__ Bl, __hip_bfloat16* __restrict__ z1b,
        float* __restrict__ es1, float* __restrict__ ed1) {
    int q = L >> 4, L15 = L & 15;
    int rowA = n0 + L15;
    int rrA = rowA < N_NODES ? rowA : N_NODES - 1;
    const float* hrow = h + (size_t)rrA * IN_DIM + q * 8;

    f32x4 acc[9];
#pragma unroll
    for (int nt = 0; nt < 9; nt++) acc[nt] = (f32x4)(0.f);

    float4 x0 = *(const float4*)(hrow);
    float4 x1 = *(const float4*)(hrow + 4);

#pragma unroll
    for (int s = 0; s < 8; s++) {
        int sn = (s < 7) ? s + 1 : 7;
        float4 p0 = *(const float4*)(hrow + sn * 32);
        float4 p1 = *(const float4*)(hrow + sn * 32 + 4);

        float xs[8] = {x0.x, x0.y, x0.z, x0.w, x1.x, x1.y, x1.z, x1.w};
        bf16x8 ah, al;
#pragma unroll
        for (int j = 0; j < 8; j++) {
            short hi, lo;
            splitf(xs[j], hi, lo);
            ah[j] = hi;
            al[j] = lo;
        }

        const bf16x8* bhp = (const bf16x8*)(Bh + ((size_t)s * 9 * 64) * 8 + (size_t)L * 8);
        const bf16x8* blp = (const bf16x8*)(Bl + ((size_t)s * 9 * 64) * 8 + (size_t)L * 8);
#pragma unroll
        for (int nt = 0; nt < 9; nt++) {
            bf16x8 bh = bhp[nt * 64];
            acc[nt] = __builtin_amdgcn_mfma_f32_16x16x32_bf16(ah, bh, acc[nt], 0, 0, 0);
            acc[nt] = __builtin_amdgcn_mfma_f32_16x16x32_bf16(al, bh, acc[nt], 0, 0, 0);
        }
        {
            bf16x8 bl8 = blp[8 * 64];
            acc[8] = __builtin_amdgcn_mfma_f32_16x16x32_bf16(ah, bl8, acc[8], 0, 0, 0);
        }
        x0 = p0;
        x1 = p1;
    }

    // permuted-layout epilogue: per row, per head, one dword store
    // (position p = h*32 + L15*2 + b, b selects nt=2h / 2h+1) — 16 coalesced
    // dword stores replacing 32 scalar 2B stores.
#pragma unroll
    for (int r = 0; r < 4; r++) {
        int rowc = n0 + q * 4 + r;
        if (rowc < N_NODES) {
            unsigned* zp = (unsigned*)(z1b + (size_t)rowc * 128);
#pragma unroll
            for (int hh = 0; hh < 4; hh++) {
                unsigned wv = (unsigned)rne_bf16(acc[2 * hh][r]) |
                              ((unsigned)rne_bf16(acc[2 * hh + 1][r]) << 16);
                zp[hh * 16 + L15] = wv;
            }
            if (L15 < 4) es1[rowc * HEADS + L15] = acc[8][r];
            else if (L15 < 8) ed1[rowc * HEADS + (L15 - 4)] = acc[8][r];
        }
    }
}

// ---------------- K2: scan1 (blocks 0..48) + proj1 (blocks 49..) ----------------
// scan1 depends only on count (K1); proj1 only on B-packs + h (K1). No
// intra-kernel dependency; the fully-parallel scan hides under proj1.

__global__ void __launch_bounds__(256) scan_proj1_kernel(
        const float* __restrict__ h, const unsigned short* __restrict__ Bh,
        const unsigned short* __restrict__ Bl, __hip_bfloat16* __restrict__ z1b,
        float* __restrict__ es1, float* __restrict__ ed1,
        const int* __restrict__ count, int* __restrict__ rs_local,
        int* __restrict__ cursor, int* __restrict__ bs_prefix) {
    if (blockIdx.x < SCAN_BLOCKS) {
        __shared__ int sdata[256];
        scan1_body(blockIdx.x, threadIdx.x, count, rs_local, cursor, bs_prefix, sdata);
        return;
    }
    int wave = threadIdx.x >> 6;
    int L = threadIdx.x & 63;
    int n0 = (blockIdx.x - SCAN_BLOCKS) * 64 + wave * 16;
    proj1_body(n0, L, h, Bh, Bl, z1b, es1, ed1);
}

// ---------------- K3: scatter src into CSR order (cursor atomics, no rank) ----------

__global__ void scatter_kernel(const int* __restrict__ src, const int* __restrict__ dst,
                               int* __restrict__ cursor, const int* __restrict__ bs_prefix,
                               int* __restrict__ esrc) {
    int i = blockIdx.x * blockDim.x + threadIdx.x;
    if (i < N_EDGES) {
        int d = dst[i];
        int pos = atomicAdd(&cursor[d], 1);
        esrc[pos + bs_prefix[d >> 10]] = src[i];
    }
}

// ---------------- K4: Layer 1 aggregation + ELU (position-blind, unchanged) --------

__global__ void __launch_bounds__(256) agg1_kernel(
        const __hip_bfloat16* __restrict__ z1b, const float* __restrict__ es1,
        const float* __restrict__ ed1, const int* __restrict__ rs_local,
        const int* __restrict__ bs_prefix, const int* __restrict__ count,
        const int* __restrict__ esrc, __hip_bfloat16* __restrict__ h1b) {
    int v = blockIdx.x * 4 + (threadIdx.x >> 6);
    int L = threadIdx.x & 63;
    int sub = L >> 4;
    int c16 = L & 15;
    int hd = c16 >> 2;
    int beg = rs_local[v] + bs_prefix[v >> 10], deg = count[v];
    float edv = ed1[v * HEADS + hd];
    const int* ep = esrc + beg;
    float lacc = 0.f;
    float acc[8];
#pragma unroll
    for (int i = 0; i < 8; i++) acc[i] = 0.f;
    const uint4* zq = (const uint4*)z1b;   // row = 16 uint4

    for (int j0 = 0; j0 < deg; j0 += 32) {
        int se[8];
        uint4 u[8];
        float ev[8];
#pragma unroll
        for (int g = 0; g < 8; g++) {
            if (j0 + g * 4 < deg) {               // wave-uniform
                int e = j0 + g * 4 + sub;
                se[g] = ep[(e < deg) ? e : 0];
            }
        }
#pragma unroll
        for (int g = 0; g < 8; g++) {
            if (j0 + g * 4 < deg) {
                u[g] = zq[(size_t)se[g] * 16 + c16];
                ev[g] = es1[se[g] * HEADS + hd];
            }
        }
#pragma unroll
        for (int g = 0; g < 8; g++) {
            if (j0 + g * 4 < deg) {
                bool val = (j0 + g * 4 + sub) < deg;
                float q = val ? __expf(lrelu(ev[g] + edv)) : 0.f;
                lacc += q;
                acc[0] = fmaf(q, bflo(u[g].x), acc[0]);
                acc[1] = fmaf(q, bfhi(u[g].x), acc[1]);
                acc[2] = fmaf(q, bflo(u[g].y), acc[2]);
                acc[3] = fmaf(q, bfhi(u[g].y), acc[3]);
                acc[4] = fmaf(q, bflo(u[g].z), acc[4]);
                acc[5] = fmaf(q, bfhi(u[g].z), acc[5]);
                acc[6] = fmaf(q, bflo(u[g].w), acc[6]);
                acc[7] = fmaf(q, bfhi(u[g].w), acc[7]);
            }
        }
    }
    lacc += __shfl_xor(lacc, 1);
    lacc += __shfl_xor(lacc, 2);
    lacc += __shfl_xor(lacc, 16);
    lacc += __shfl_xor(lacc, 32);
    lacc *= 0.25f;
#pragma unroll
    for (int i = 0; i < 8; i++) {
        acc[i] += __shfl_xor(acc[i], 16);
        acc[i] += __shfl_xor(acc[i], 32);
    }
    if (L < 16) {
        float inv = (deg > 0) ? 1.f / lacc : 0.f;
        unsigned w[4];
#pragma unroll
        for (int i = 0; i < 4; i++) {
            float r0 = acc[2 * i] * inv;
            float r1 = acc[2 * i + 1] * inv;
            r0 = r0 > 0.f ? r0 : __expf(r0) - 1.f;   // elu
            r1 = r1 > 0.f ? r1 : __expf(r1) - 1.f;
            w[i] = (unsigned)rne_bf16(r0) | ((unsigned)rne_bf16(r1) << 16);
        }
        uint4* dstp = (uint4*)(h1b + (size_t)v * 128 + c16 * 8);
        *dstp = make_uint4(w[0], w[1], w[2], w[3]);
    }
}

// ---------------- K5: Layer 2 projection via MFMA (Bf2 pack pre-permuted) ----------

__global__ void __launch_bounds__(256) proj2_mfma(
        const __hip_bfloat16* __restrict__ h1b, const unsigned short* __restrict__ Bh,
        const unsigned short* __restrict__ Bl, __hip_bfloat16* __restrict__ z2b,
        float* __restrict__ es2, float* __restrict__ ed2) {
    int tid = threadIdx.x;
    int wave = tid >> 6;
    int L = tid & 63;
    int q = L >> 4, L15 = L & 15;
    int n0 = blockIdx.x * 64 + wave * 16;

    int rowA = n0 + L15;
    int rrA = rowA < N_NODES ? rowA : N_NODES - 1;
    const bf16x8* hq = (const bf16x8*)(h1b + (size_t)rrA * 128);

    bf16x8 av[4];
#pragma unroll
    for (int s = 0; s < 4; s++) av[s] = hq[s * 4 + q];

    f32x4 acc[5];
#pragma unroll
    for (int nt = 0; nt < 5; nt++) acc[nt] = (f32x4)(0.f);

#pragma unroll
    for (int s = 0; s < 4; s++) {
        const bf16x8* bhp = (const bf16x8*)(Bh + ((size_t)s * 5 * 64) * 8 + (size_t)L * 8);
        const bf16x8* blp = (const bf16x8*)(Bl + ((size_t)s * 5 * 64) * 8 + (size_t)L * 8);
#pragma unroll
        for (int nt = 0; nt < 5; nt++)
            acc[nt] = __builtin_amdgcn_mfma_f32_16x16x32_bf16(av[s], bhp[nt * 64], acc[nt], 0, 0, 0);
        acc[4] = __builtin_amdgcn_mfma_f32_16x16x32_bf16(av[s], blp[4 * 64], acc[4], 0, 0, 0);
    }

#pragma unroll
    for (int r = 0; r < 4; r++) {
        int rowc = n0 + q * 4 + r;
        if (rowc < N_NODES) {
#pragma unroll
            for (int nt = 0; nt < 4; nt++)
                z2b[(size_t)rowc * OUT_DIM + nt * 16 + L15] = __float2bfloat16(acc[nt][r]);
            if (L15 == 0) es2[rowc] = acc[4][r];
            else if (L15 == 1) ed2[rowc] = acc[4][r];
        }
    }
}

// ---------------- K6: Layer 2 aggregation (final output) ----------------

__global__ void __launch_bounds__(256) agg2_kernel(
        const __hip_bfloat16* __restrict__ z2b, const float* __restrict__ es2,
        const float* __restrict__ ed2, const int* __restrict__ rs_local,
        const int* __restrict__ bs_prefix, const int* __restrict__ count,
        const int* __restrict__ esrc, float* __restrict__ out) {
    int v = blockIdx.x * 4 + (threadIdx.x >> 6);
    int L = threadIdx.x & 63;
    int sub = L >> 3;
    int c8 = L & 7;
    int beg = rs_local[v] + bs_prefix[v >> 10], deg = count[v];
    float edv = ed2[v];
    const int* ep = esrc + beg;
    float lacc = 0.f;
    float acc[8];
#pragma unroll
    for (int i = 0; i < 8; i++) acc[i] = 0.f;
    const uint4* zq = (const uint4*)z2b;

    for (int j0 = 0; j0 < deg; j0 += 32) {
        int se[4];
        uint4 u[4];
        float ev[4];
#pragma unroll
        for (int g = 0; g < 4; g++) {
            if (j0 + g * 8 < deg) {
                int e = j0 + g * 8 + sub;
                se[g] = ep[(e < deg) ? e : 0];
            }
        }
#pragma unroll
        for (int g = 0; g < 4; g++) {
            if (j0 + g * 8 < deg) {
                u[g] = zq[(size_t)se[g] * 8 + c8];
                ev[g] = es2[se[g]];
            }
        }
#pragma unroll
        for (int g = 0; g < 4; g++) {
            if (j0 + g * 8 < deg) {
                bool val = (j0 + g * 8 + sub) < deg;
                float q = val ? __expf(lrelu(ev[g] + edv)) : 0.f;
                lacc += q;
                acc[0] = fmaf(q, bflo(u[g].x), acc[0]);
                acc[1] = fmaf(q, bfhi(u[g].x), acc[1]);
                acc[2] = fmaf(q, bflo(u[g].y), acc[2]);
                acc[3] = fmaf(q, bfhi(u[g].y), acc[3]);
                acc[4] = fmaf(q, bflo(u[g].z), acc[4]);
                acc[5] = fmaf(q, bfhi(u[g].z), acc[5]);
                acc[6] = fmaf(q, bflo(u[g].w), acc[6]);
                acc[7] = fmaf(q, bfhi(u[g].w), acc[7]);
            }
        }
    }
    lacc += __shfl_xor(lacc, 8);
    lacc += __shfl_xor(lacc, 16);
    lacc += __shfl_xor(lacc, 32);
#pragma unroll
    for (int i = 0; i < 8; i++) {
        acc[i] += __shfl_xor(acc[i], 8);
        acc[i] += __shfl_xor(acc[i], 16);
        acc[i] += __shfl_xor(acc[i], 32);
    }
    if (L < 8) {
        float inv = (deg > 0) ? 1.f / lacc : 0.f;
        float4 r0, r1;
#pragma unroll
        for (int i = 0; i < 8; i++) {
            float r = acc[i] * inv;
            if (i < 4) (&r0.x)[i] = r;
            else (&r1.x)[i - 4] = r;
        }
        float* dstp = out + (size_t)v * OUT_DIM + c8 * 8;
        *(float4*)dstp = r0;
        *(float4*)(dstp + 4) = r1;
    }
}

// ---------------- launch ----------------

extern "C" void kernel_launch(void* const* d_in, const int* in_sizes, int n_in,
                              void* d_out, int out_size, void* d_ws, size_t ws_size,
                              hipStream_t stream) {
    const float* h  = (const float*)d_in[0];
    const int* src  = (const int*)d_in[1];
    const int* dst  = (const int*)d_in[2];
    const float* W1 = (const float*)d_in[3];
    const float* a1 = (const float*)d_in[4];
    const float* W2 = (const float*)d_in[5];
    const float* a2 = (const float*)d_in[6];
    float* out = (float*)d_out;

    char* w = (char*)d_ws;
    size_t off = 0;
    auto alloc = [&](size_t bytes) {
        void* p = w + off;
        off = (off + bytes + 255) & ~(size_t)255;
        return p;
    };
    __hip_bfloat16* z1b = (__hip_bfloat16*)alloc((size_t)N_NODES * 128 * 2);
    float* es1 = (float*)alloc((size_t)N_NODES * HEADS * 4);
    float* ed1 = (float*)alloc((size_t)N_NODES * HEADS * 4);
    __hip_bfloat16* h1b = (__hip_bfloat16*)alloc((size_t)N_NODES * 128 * 2);
    __hip_bfloat16* z2b = (__hip_bfloat16*)alloc((size_t)N_NODES * OUT_DIM * 2);
    float* es2 = (float*)alloc((size_t)N_NODES * 4);
    float* ed2 = (float*)alloc((size_t)N_NODES * 4);
    // count + bs_prefix share one allocation (zeroed together by one memset)
    int* count     = (int*)alloc((size_t)(N_NODES + 64) * 4);
    int* bs_prefix = count + N_NODES;
    int* rs_local  = (int*)alloc((size_t)N_NODES * 4);
    int* cursor    = (int*)alloc((size_t)N_NODES * 4);
    int* esrc      = (int*)alloc((size_t)N_EDGES * 4);
    unsigned short* Bf1h = (unsigned short*)alloc((size_t)8 * 9 * 64 * 8 * 2);
    unsigned short* Bf1l = (unsigned short*)alloc((size_t)8 * 9 * 64 * 8 * 2);
    unsigned short* Bf2h = (unsigned short*)alloc((size_t)4 * 5 * 64 * 8 * 2);
    unsigned short* Bf2l = (unsigned short*)alloc((size_t)4 * 5 * 64 * 8 * 2);

    // count = 0, bs_prefix = 0 (one graph-capture-legal async memset)
    hipMemsetAsync(count, 0, (size_t)(N_NODES + 64) * 4, stream);

    // K1: prep (256 blocks) || histogram (3125 blocks)
    prep_hist_kernel<<<256 + HIST_BLOCKS, 256, 0, stream>>>(
        W1, a1, W2, a2, Bf1h, Bf1l, Bf2h, Bf2l, dst, count);

    // K2: parallel scan (49 blocks) || proj1 (782 blocks)
    scan_proj1_kernel<<<SCAN_BLOCKS + MBLK, 256, 0, stream>>>(
        h, Bf1h, Bf1l, z1b, es1, ed1, count, rs_local, cursor, bs_prefix);

    // K3: scatter src into CSR order
    scatter_kernel<<<HIST_BLOCKS, 256, 0, stream>>>(src, dst, cursor, bs_prefix, esrc);

    // K4..K6: back-end
    agg1_kernel<<<N_NODES / 4, 256, 0, stream>>>(
        z1b, es1, ed1, rs_local, bs_prefix, count, esrc, h1b);
    proj2_mfma<<<MBLK, 256, 0, stream>>>(h1b, Bf2h, Bf2l, z2b, es2, ed2);
    agg2_kernel<<<N_NODES / 4, 256, 0, stream>>>(
        z2b, es2, ed2, rs_local, bs_prefix, count, esrc, out);
}

// Round 7
// 211.329 us; speedup vs baseline: 1.2493x; 1.2493x over previous
//
#include <hip/hip_runtime.h>
#include <hip/hip_bf16.h>
#include <math.h>

#define N_NODES 50000
#define N_EDGES 800000
#define IN_DIM 256
#define HID 32
#define HEADS 4
#define OUT_DIM 64

#define SCAN_CHUNK 1024
#define SCAN_BLOCKS ((N_NODES + SCAN_CHUNK - 1) / SCAN_CHUNK)  // 49
#define HIST_BLOCKS ((N_EDGES + 255) / 256)   // 3125
#define MBLK ((N_NODES + 63) / 64)            // 782

typedef __attribute__((ext_vector_type(8))) short bf16x8;
typedef __attribute__((ext_vector_type(4))) float f32x4;

__device__ __forceinline__ float lrelu(float e) { return e > 0.f ? e : 0.01f * e; }
__device__ __forceinline__ float bflo(unsigned u) { return __uint_as_float(u << 16); }
__device__ __forceinline__ float bfhi(unsigned u) { return __uint_as_float(u & 0xffff0000u); }

// RNE float->bf16
__device__ __forceinline__ unsigned short rne_bf16(float x) {
    unsigned u = __float_as_uint(x);
    unsigned r = u + 0x7fffu + ((u >> 16) & 1u);
    return (unsigned short)(r >> 16);
}

// A-operand split (truncate hi + residual)
__device__ __forceinline__ void splitf(float x, short& hi, short& lo) {
    unsigned u = __float_as_uint(x);
    unsigned short h = (unsigned short)(u >> 16);
    float hf = __uint_as_float(((unsigned)h) << 16);
    float l = x - hf;
    unsigned short lb = (unsigned short)(__float_as_uint(l) >> 16);
    hi = (short)h;
    lo = (short)lb;
}

// ---------------- B-pack prep body ----------------
// z1b/h1b use an internal within-head channel permutation:
//   stored position p(ch) = (ch>>5)*32 + (ch&15)*2 + ((ch>>4)&1)
// (so proj1's epilogue stores are contiguous dwords). agg1 is position-blind
// (head of every 16B block preserved). Only consequence: B2 pack slot k
// fetches W2's TRUE row ck(k) = (2*(k>>5)+(k&1))*16 + ((k&31)>>1).

__device__ __forceinline__ void prep_body(int k, int c,
        const float* __restrict__ W1, const float* __restrict__ a1,
        const float* __restrict__ W2, const float* __restrict__ a2,
        unsigned short* __restrict__ B1h, unsigned short* __restrict__ B1l,
        unsigned short* __restrict__ B2h, unsigned short* __restrict__ B2l) {
    if (c < 144) {
        float val = 0.f;
        if (c < 128) {
            val = W1[(size_t)(c >> 5) * IN_DIM * HID + (size_t)k * HID + (c & 31)];
        } else if (c < 136) {
            int j = c - 128;
            int hd = (j < 4) ? j : (j - 4);
            int off = (j < 4) ? 0 : HID;
            const float* Wp = W1 + (size_t)hd * IN_DIM * HID + (size_t)k * HID;
            const float* ap = a1 + hd * 2 * HID + off;
            float s = 0.f;
            for (int o = 0; o < HID; o++) s += Wp[o] * ap[o];
            val = s;
        }
        unsigned short hi = rne_bf16(val);
        float hf = __uint_as_float(((unsigned)hi) << 16);
        unsigned short lo = rne_bf16(val - hf);
        int s_ = k >> 5, q = (k >> 3) & 3, j8 = k & 7;
        int nt = c >> 4, L = q * 16 + (c & 15);
        size_t idx = (((size_t)s_ * 9 + nt) * 64 + L) * 8 + j8;
        B1h[idx] = hi;
        B1l[idx] = lo;
    } else if (c >= 160 && c < 240 && k < 128) {
        int c2 = c - 160;
        int ck = (2 * (k >> 5) + (k & 1)) * 16 + ((k & 31) >> 1);
        float val = 0.f;
        if (c2 < 64) {
            val = W2[(size_t)ck * OUT_DIM + c2];
        } else if (c2 < 66) {
            const float* ap = a2 + (c2 - 64) * OUT_DIM;
            const float* Wp = W2 + (size_t)ck * OUT_DIM;
            float s = 0.f;
            for (int o = 0; o < OUT_DIM; o++) s += Wp[o] * ap[o];
            val = s;
        }
        unsigned short hi = rne_bf16(val);
        float hf = __uint_as_float(((unsigned)hi) << 16);
        unsigned short lo = rne_bf16(val - hf);
        int s_ = k >> 5, q = (k >> 3) & 3, j8 = k & 7;
        int nt = c2 >> 4, L = q * 16 + (c2 & 15);
        size_t idx = (((size_t)s_ * 5 + nt) * 64 + L) * 8 + j8;
        B2h[idx] = hi;
        B2l[idx] = lo;
    }
}

// ---------------- K0: prep + zero count/bs_prefix ----------------

__global__ void __launch_bounds__(256) prep_kernel(
        const float* __restrict__ W1, const float* __restrict__ a1,
        const float* __restrict__ W2, const float* __restrict__ a2,
        unsigned short* __restrict__ B1h, unsigned short* __restrict__ B1l,
        unsigned short* __restrict__ B2h, unsigned short* __restrict__ B2l,
        int* __restrict__ count) {
    int gid = blockIdx.x * 256 + threadIdx.x;
    if (gid < N_NODES + 64) count[gid] = 0;   // count + bs_prefix (contiguous)
    prep_body(blockIdx.x, threadIdx.x, W1, a1, W2, a2, B1h, B1l, B2h, B2l);
}

// ---------------- Layer-1 projection body: one wave handles rows n0..n0+15 ----------------

__device__ __forceinline__ void proj1_body(int n0, int L,
        const float* __restrict__ h, const unsigned short* __restrict__ Bh,
        const unsigned short* __restrict__ Bl, __hip_bfloat16* __restrict__ z1b,
        float* __restrict__ es1, float* __restrict__ ed1) {
    int q = L >> 4, L15 = L & 15;
    int rowA = n0 + L15;
    int rrA = rowA < N_NODES ? rowA : N_NODES - 1;
    const float* hrow = h + (size_t)rrA * IN_DIM + q * 8;

    f32x4 acc[9];
#pragma unroll
    for (int nt = 0; nt < 9; nt++) acc[nt] = (f32x4)(0.f);

    float4 x0 = *(const float4*)(hrow);
    float4 x1 = *(const float4*)(hrow + 4);

#pragma unroll
    for (int s = 0; s < 8; s++) {
        int sn = (s < 7) ? s + 1 : 7;
        float4 p0 = *(const float4*)(hrow + sn * 32);
        float4 p1 = *(const float4*)(hrow + sn * 32 + 4);

        float xs[8] = {x0.x, x0.y, x0.z, x0.w, x1.x, x1.y, x1.z, x1.w};
        bf16x8 ah, al;
#pragma unroll
        for (int j = 0; j < 8; j++) {
            short hi, lo;
            splitf(xs[j], hi, lo);
            ah[j] = hi;
            al[j] = lo;
        }

        const bf16x8* bhp = (const bf16x8*)(Bh + ((size_t)s * 9 * 64) * 8 + (size_t)L * 8);
        const bf16x8* blp = (const bf16x8*)(Bl + ((size_t)s * 9 * 64) * 8 + (size_t)L * 8);
#pragma unroll
        for (int nt = 0; nt < 9; nt++) {
            bf16x8 bh = bhp[nt * 64];
            acc[nt] = __builtin_amdgcn_mfma_f32_16x16x32_bf16(ah, bh, acc[nt], 0, 0, 0);
            acc[nt] = __builtin_amdgcn_mfma_f32_16x16x32_bf16(al, bh, acc[nt], 0, 0, 0);
        }
        {
            bf16x8 bl8 = blp[8 * 64];
            acc[8] = __builtin_amdgcn_mfma_f32_16x16x32_bf16(ah, bl8, acc[8], 0, 0, 0);
        }
        x0 = p0;
        x1 = p1;
    }

    // permuted-layout epilogue: per row, per head, one dword store —
    // 16 coalesced dword stores replacing 32 scalar 2B stores.
#pragma unroll
    for (int r = 0; r < 4; r++) {
        int rowc = n0 + q * 4 + r;
        if (rowc < N_NODES) {
            unsigned* zp = (unsigned*)(z1b + (size_t)rowc * 128);
#pragma unroll
            for (int hh = 0; hh < 4; hh++) {
                unsigned wv = (unsigned)rne_bf16(acc[2 * hh][r]) |
                              ((unsigned)rne_bf16(acc[2 * hh + 1][r]) << 16);
                zp[hh * 16 + L15] = wv;
            }
            if (L15 < 4) es1[rowc * HEADS + L15] = acc[8][r];
            else if (L15 < 8) ed1[rowc * HEADS + (L15 - 4)] = acc[8][r];
        }
    }
}

// ---------------- K1: proj1 (blocks 0..MBLK-1) || histogram (blocks MBLK..) --------
// proj1 needs B-packs + h (K0); hist needs dst + zeroed count (K0). Disjoint
// data, complementary pipes (MFMA/HBM vs atomic) — measured max-like (R4).

__global__ void __launch_bounds__(256) proj1_hist_kernel(
        const float* __restrict__ h, const unsigned short* __restrict__ Bh,
        const unsigned short* __restrict__ Bl, __hip_bfloat16* __restrict__ z1b,
        float* __restrict__ es1, float* __restrict__ ed1,
        const int* __restrict__ dst, int* __restrict__ count,
        int* __restrict__ rank) {
    int bid = blockIdx.x;
    if (bid < MBLK) {
        int wave = threadIdx.x >> 6;
        int L = threadIdx.x & 63;
        proj1_body(bid * 64 + wave * 16, L, h, Bh, Bl, z1b, es1, ed1);
    } else {
        int i = (bid - MBLK) * 256 + threadIdx.x;
        if (i < N_EDGES) rank[i] = atomicAdd(&count[dst[i]], 1);
    }
}

// ---------------- K2: scan1 — per-chunk scan + cross-chunk atomic prefix ----------
// Global offset of node v = rs_local[v] + bs_prefix[v>>10].

__global__ void __launch_bounds__(256) scan_kernel(
        const int* __restrict__ count, int* __restrict__ rs_local,
        int* __restrict__ bs_prefix) {
    __shared__ int sdata[256];
    int bid = blockIdx.x;
    int t = threadIdx.x;
    int base = bid * SCAN_CHUNK + t * 4;
    int v[4];
    int s = 0;
#pragma unroll
    for (int j = 0; j < 4; j++) {
        int idx = base + j;
        int x = (idx < N_NODES) ? count[idx] : 0;
        v[j] = x;
        s += x;
    }
    sdata[t] = s;
    __syncthreads();
    for (int off = 1; off < 256; off <<= 1) {
        int u = (t >= off) ? sdata[t - off] : 0;
        __syncthreads();
        sdata[t] += u;
        __syncthreads();
    }
    int excl = sdata[t] - s;
#pragma unroll
    for (int j = 0; j < 4; j++) {
        int idx = base + j;
        if (idx < N_NODES) rs_local[idx] = excl;
        excl += v[j];
    }
    if (t > bid && t < SCAN_BLOCKS) atomicAdd(&bs_prefix[t], sdata[255]);
}

// ---------------- K3: scatter src into CSR order (rank-based) ----------------

__global__ void scatter_kernel(const int* __restrict__ src, const int* __restrict__ dst,
                               const int* __restrict__ rank, const int* __restrict__ rs_local,
                               const int* __restrict__ bs_prefix, int* __restrict__ esrc) {
    int i = blockIdx.x * blockDim.x + threadIdx.x;
    if (i < N_EDGES) {
        int d = dst[i];
        esrc[rs_local[d] + bs_prefix[d >> 10] + rank[i]] = src[i];
    }
}

// ---------------- K4: Layer 1 aggregation + ELU (position-blind) ----------------

__global__ void __launch_bounds__(256) agg1_kernel(
        const __hip_bfloat16* __restrict__ z1b, const float* __restrict__ es1,
        const float* __restrict__ ed1, const int* __restrict__ rs_local,
        const int* __restrict__ bs_prefix, const int* __restrict__ count,
        const int* __restrict__ esrc, __hip_bfloat16* __restrict__ h1b) {
    int v = blockIdx.x * 4 + (threadIdx.x >> 6);
    int L = threadIdx.x & 63;
    int sub = L >> 4;
    int c16 = L & 15;
    int hd = c16 >> 2;
    int beg = rs_local[v] + bs_prefix[v >> 10], deg = count[v];
    float edv = ed1[v * HEADS + hd];
    const int* ep = esrc + beg;
    float lacc = 0.f;
    float acc[8];
#pragma unroll
    for (int i = 0; i < 8; i++) acc[i] = 0.f;
    const uint4* zq = (const uint4*)z1b;   // row = 16 uint4

    for (int j0 = 0; j0 < deg; j0 += 32) {
        int se[8];
        uint4 u[8];
        float ev[8];
#pragma unroll
        for (int g = 0; g < 8; g++) {
            if (j0 + g * 4 < deg) {               // wave-uniform
                int e = j0 + g * 4 + sub;
                se[g] = ep[(e < deg) ? e : 0];
            }
        }
#pragma unroll
        for (int g = 0; g < 8; g++) {
            if (j0 + g * 4 < deg) {
                u[g] = zq[(size_t)se[g] * 16 + c16];
                ev[g] = es1[se[g] * HEADS + hd];
            }
        }
#pragma unroll
        for (int g = 0; g < 8; g++) {
            if (j0 + g * 4 < deg) {
                bool val = (j0 + g * 4 + sub) < deg;
                float q = val ? __expf(lrelu(ev[g] + edv)) : 0.f;
                lacc += q;
                acc[0] = fmaf(q, bflo(u[g].x), acc[0]);
                acc[1] = fmaf(q, bfhi(u[g].x), acc[1]);
                acc[2] = fmaf(q, bflo(u[g].y), acc[2]);
                acc[3] = fmaf(q, bfhi(u[g].y), acc[3]);
                acc[4] = fmaf(q, bflo(u[g].z), acc[4]);
                acc[5] = fmaf(q, bfhi(u[g].z), acc[5]);
                acc[6] = fmaf(q, bflo(u[g].w), acc[6]);
                acc[7] = fmaf(q, bfhi(u[g].w), acc[7]);
            }
        }
    }
    lacc += __shfl_xor(lacc, 1);
    lacc += __shfl_xor(lacc, 2);
    lacc += __shfl_xor(lacc, 16);
    lacc += __shfl_xor(lacc, 32);
    lacc *= 0.25f;
#pragma unroll
    for (int i = 0; i < 8; i++) {
        acc[i] += __shfl_xor(acc[i], 16);
        acc[i] += __shfl_xor(acc[i], 32);
    }
    if (L < 16) {
        float inv = (deg > 0) ? 1.f / lacc : 0.f;
        unsigned w[4];
#pragma unroll
        for (int i = 0; i < 4; i++) {
            float r0 = acc[2 * i] * inv;
            float r1 = acc[2 * i + 1] * inv;
            r0 = r0 > 0.f ? r0 : __expf(r0) - 1.f;   // elu
            r1 = r1 > 0.f ? r1 : __expf(r1) - 1.f;
            w[i] = (unsigned)rne_bf16(r0) | ((unsigned)rne_bf16(r1) << 16);
        }
        uint4* dstp = (uint4*)(h1b + (size_t)v * 128 + c16 * 8);
        *dstp = make_uint4(w[0], w[1], w[2], w[3]);
    }
}

// ---------------- K5: Layer 2 projection via MFMA (Bf2 pack pre-permuted) ----------

__global__ void __launch_bounds__(256) proj2_mfma(
        const __hip_bfloat16* __restrict__ h1b, const unsigned short* __restrict__ Bh,
        const unsigned short* __restrict__ Bl, __hip_bfloat16* __restrict__ z2b,
        float* __restrict__ es2, float* __restrict__ ed2) {
    int tid = threadIdx.x;
    int wave = tid >> 6;
    int L = tid & 63;
    int q = L >> 4, L15 = L & 15;
    int n0 = blockIdx.x * 64 + wave * 16;

    int rowA = n0 + L15;
    int rrA = rowA < N_NODES ? rowA : N_NODES - 1;
    const bf16x8* hq = (const bf16x8*)(h1b + (size_t)rrA * 128);

    bf16x8 av[4];
#pragma unroll
    for (int s = 0; s < 4; s++) av[s] = hq[s * 4 + q];

    f32x4 acc[5];
#pragma unroll
    for (int nt = 0; nt < 5; nt++) acc[nt] = (f32x4)(0.f);

#pragma unroll
    for (int s = 0; s < 4; s++) {
        const bf16x8* bhp = (const bf16x8*)(Bh + ((size_t)s * 5 * 64) * 8 + (size_t)L * 8);
        const bf16x8* blp = (const bf16x8*)(Bl + ((size_t)s * 5 * 64) * 8 + (size_t)L * 8);
#pragma unroll
        for (int nt = 0; nt < 5; nt++)
            acc[nt] = __builtin_amdgcn_mfma_f32_16x16x32_bf16(av[s], bhp[nt * 64], acc[nt], 0, 0, 0);
        acc[4] = __builtin_amdgcn_mfma_f32_16x16x32_bf16(av[s], blp[4 * 64], acc[4], 0, 0, 0);
    }

#pragma unroll
    for (int r = 0; r < 4; r++) {
        int rowc = n0 + q * 4 + r;
        if (rowc < N_NODES) {
#pragma unroll
            for (int nt = 0; nt < 4; nt++)
                z2b[(size_t)rowc * OUT_DIM + nt * 16 + L15] = __float2bfloat16(acc[nt][r]);
            if (L15 == 0) es2[rowc] = acc[4][r];
            else if (L15 == 1) ed2[rowc] = acc[4][r];
        }
    }
}

// ---------------- K6: Layer 2 aggregation (final output) ----------------

__global__ void __launch_bounds__(256) agg2_kernel(
        const __hip_bfloat16* __restrict__ z2b, const float* __restrict__ es2,
        const float* __restrict__ ed2, const int* __restrict__ rs_local,
        const int* __restrict__ bs_prefix, const int* __restrict__ count,
        const int* __restrict__ esrc, float* __restrict__ out) {
    int v = blockIdx.x * 4 + (threadIdx.x >> 6);
    int L = threadIdx.x & 63;
    int sub = L >> 3;
    int c8 = L & 7;
    int beg = rs_local[v] + bs_prefix[v >> 10], deg = count[v];
    float edv = ed2[v];
    const int* ep = esrc + beg;
    float lacc = 0.f;
    float acc[8];
#pragma unroll
    for (int i = 0; i < 8; i++) acc[i] = 0.f;
    const uint4* zq = (const uint4*)z2b;

    for (int j0 = 0; j0 < deg; j0 += 32) {
        int se[4];
        uint4 u[4];
        float ev[4];
#pragma unroll
        for (int g = 0; g < 4; g++) {
            if (j0 + g * 8 < deg) {
                int e = j0 + g * 8 + sub;
                se[g] = ep[(e < deg) ? e : 0];
            }
        }
#pragma unroll
        for (int g = 0; g < 4; g++) {
            if (j0 + g * 8 < deg) {
                u[g] = zq[(size_t)se[g] * 8 + c8];
                ev[g] = es2[se[g]];
            }
        }
#pragma unroll
        for (int g = 0; g < 4; g++) {
            if (j0 + g * 8 < deg) {
                bool val = (j0 + g * 8 + sub) < deg;
                float q = val ? __expf(lrelu(ev[g] + edv)) : 0.f;
                lacc += q;
                acc[0] = fmaf(q, bflo(u[g].x), acc[0]);
                acc[1] = fmaf(q, bfhi(u[g].x), acc[1]);
                acc[2] = fmaf(q, bflo(u[g].y), acc[2]);
                acc[3] = fmaf(q, bfhi(u[g].y), acc[3]);
                acc[4] = fmaf(q, bflo(u[g].z), acc[4]);
                acc[5] = fmaf(q, bfhi(u[g].z), acc[5]);
                acc[6] = fmaf(q, bflo(u[g].w), acc[6]);
                acc[7] = fmaf(q, bfhi(u[g].w), acc[7]);
            }
        }
    }
    lacc += __shfl_xor(lacc, 8);
    lacc += __shfl_xor(lacc, 16);
    lacc += __shfl_xor(lacc, 32);
#pragma unroll
    for (int i = 0; i < 8; i++) {
        acc[i] += __shfl_xor(acc[i], 8);
        acc[i] += __shfl_xor(acc[i], 16);
        acc[i] += __shfl_xor(acc[i], 32);
    }
    if (L < 8) {
        float inv = (deg > 0) ? 1.f / lacc : 0.f;
        float4 r0, r1;
#pragma unroll
        for (int i = 0; i < 8; i++) {
            float r = acc[i] * inv;
            if (i < 4) (&r0.x)[i] = r;
            else (&r1.x)[i - 4] = r;
        }
        float* dstp = out + (size_t)v * OUT_DIM + c8 * 8;
        *(float4*)dstp = r0;
        *(float4*)(dstp + 4) = r1;
    }
}

// ---------------- launch ----------------

extern "C" void kernel_launch(void* const* d_in, const int* in_sizes, int n_in,
                              void* d_out, int out_size, void* d_ws, size_t ws_size,
                              hipStream_t stream) {
    const float* h  = (const float*)d_in[0];
    const int* src  = (const int*)d_in[1];
    const int* dst  = (const int*)d_in[2];
    const float* W1 = (const float*)d_in[3];
    const float* a1 = (const float*)d_in[4];
    const float* W2 = (const float*)d_in[5];
    const float* a2 = (const float*)d_in[6];
    float* out = (float*)d_out;

    char* w = (char*)d_ws;
    size_t off = 0;
    auto alloc = [&](size_t bytes) {
        void* p = w + off;
        off = (off + bytes + 255) & ~(size_t)255;
        return p;
    };
    __hip_bfloat16* z1b = (__hip_bfloat16*)alloc((size_t)N_NODES * 128 * 2);
    float* es1 = (float*)alloc((size_t)N_NODES * HEADS * 4);
    float* ed1 = (float*)alloc((size_t)N_NODES * HEADS * 4);
    __hip_bfloat16* h1b = (__hip_bfloat16*)alloc((size_t)N_NODES * 128 * 2);
    __hip_bfloat16* z2b = (__hip_bfloat16*)alloc((size_t)N_NODES * OUT_DIM * 2);
    float* es2 = (float*)alloc((size_t)N_NODES * 4);
    float* ed2 = (float*)alloc((size_t)N_NODES * 4);
    // count + bs_prefix share one allocation (zeroed together by K0)
    int* count     = (int*)alloc((size_t)(N_NODES + 64) * 4);
    int* bs_prefix = count + N_NODES;
    int* rs_local  = (int*)alloc((size_t)N_NODES * 4);
    int* rank      = (int*)alloc((size_t)N_EDGES * 4);
    int* esrc      = (int*)alloc((size_t)N_EDGES * 4);
    unsigned short* Bf1h = (unsigned short*)alloc((size_t)8 * 9 * 64 * 8 * 2);
    unsigned short* Bf1l = (unsigned short*)alloc((size_t)8 * 9 * 64 * 8 * 2);
    unsigned short* Bf2h = (unsigned short*)alloc((size_t)4 * 5 * 64 * 8 * 2);
    unsigned short* Bf2l = (unsigned short*)alloc((size_t)4 * 5 * 64 * 8 * 2);

    // K0: B-packs + zero count/bs_prefix
    prep_kernel<<<256, 256, 0, stream>>>(W1, a1, W2, a2, Bf1h, Bf1l, Bf2h, Bf2l, count);

    // K1: proj1 (782 blocks) || histogram (3125 blocks, rank-returning atomics)
    proj1_hist_kernel<<<MBLK + HIST_BLOCKS, 256, 0, stream>>>(
        h, Bf1h, Bf1l, z1b, es1, ed1, dst, count, rank);

    // K2: parallel scan (49 blocks)
    scan_kernel<<<SCAN_BLOCKS, 256, 0, stream>>>(count, rs_local, bs_prefix);

    // K3: scatter src into CSR order
    scatter_kernel<<<HIST_BLOCKS, 256, 0, stream>>>(src, dst, rank, rs_local, bs_prefix, esrc);

    // K4..K6: back-end
    agg1_kernel<<<N_NODES / 4, 256, 0, stream>>>(
        z1b, es1, ed1, rs_local, bs_prefix, count, esrc, h1b);
    proj2_mfma<<<MBLK, 256, 0, stream>>>(h1b, Bf2h, Bf2l, z2b, es2, ed2);
    agg2_kernel<<<N_NODES / 4, 256, 0, stream>>>(
        z2b, es2, ed2, rs_local, bs_prefix, count, esrc, out);
}